// Round 2
// baseline (14249.339 us; speedup 1.0000x reference)
//
#include <hip/hip_runtime.h>
#include <hip/hip_bf16.h>
#include <math.h>

// ---------------- problem constants ----------------
#define B_        4096
#define ENC_STEPS 49     // SRC-1
#define TGT_      25
#define R_        1024
#define H_        67
#define I_        82
#define IP_       96     // input padded to multiple of 32
#define IP2_      192    // split-bf16 (hi|lo) doubled K
#define NG_       3072   // 3*R
#define FCN_      128    // fc output padded 67 -> 128
#define K2_       2048   // 2*R

typedef unsigned short u16;
typedef __attribute__((ext_vector_type(8))) short bf16x8_t;
typedef __attribute__((ext_vector_type(4))) float f32x4_t;

// ---------------- bf16 helpers ----------------
__device__ __forceinline__ float bf2f(u16 h) {
    union { unsigned int u; float f; } v; v.u = ((unsigned int)h) << 16; return v.f;
}
__device__ __forceinline__ u16 f2bf(float f) {
    union { unsigned int u; float f; } v; v.f = f;
    unsigned int u = v.u;
    u += 0x7fffu + ((u >> 16) & 1u);   // RNE
    return (u16)(u >> 16);
}
__device__ __forceinline__ float sigmf(float x) { return 1.f / (1.f + __expf(-x)); }
__device__ __forceinline__ float tanhfast(float x) { return 1.f - 2.f / (__expf(2.f * x) + 1.f); }

__device__ __forceinline__ void ldf8(const float* p, float* o) {
    float4 a = *(const float4*)p;
    float4 b = *(const float4*)(p + 4);
    o[0]=a.x; o[1]=a.y; o[2]=a.z; o[3]=a.w; o[4]=b.x; o[5]=b.y; o[6]=b.z; o[7]=b.w;
}

// ---------------- weight prep kernels ----------------
__global__ void cast_bf16_kernel(const float* __restrict__ s, u16* __restrict__ d, int n) {
    int i = blockIdx.x * 256 + threadIdx.x;
    if (i < n) d[i] = f2bf(s[i]);
}
// Wi1 [3072,82] -> [3072,192] bf16: cols 0..96 = padded Wi1, cols 96..192 = same (for hi|lo split)
__global__ void pad_wi1_dup_kernel(const float* __restrict__ s, u16* __restrict__ d) {
    int i = blockIdx.x * 256 + threadIdx.x;
    if (i >= NG_ * IP2_) return;
    int r = i / IP2_, c = i % IP2_;
    int cc = (c < IP_) ? c : c - IP_;
    d[i] = (cc < I_) ? f2bf(s[r * I_ + cc]) : (u16)0;
}
// Wfc [67,2048] -> [128,2048] bf16, zero-padded N rows
__global__ void pad_wfc_kernel(const float* __restrict__ s, u16* __restrict__ d) {
    int i = blockIdx.x * 256 + threadIdx.x;
    if (i >= FCN_ * K2_) return;
    int r = i / K2_, c = i % K2_;
    d[i] = (r < H_) ? f2bf(s[r * K2_ + c]) : (u16)0;
}

// encoder_inputs[:, t, :] -> xpad2 bf16 [B,192] (hi | lo residual)
__global__ void pad_x_kernel(const float* __restrict__ enc, u16* __restrict__ xpad, int t) {
    int i = blockIdx.x * 256 + threadIdx.x;
    if (i >= B_ * IP_) return;
    int b = i / IP_, c = i % IP_;
    float v = (c < I_) ? enc[((size_t)b * ENC_STEPS + t) * I_ + c] : 0.f;
    u16 hi = f2bf(v);
    u16 lo = f2bf(v - bf2f(hi));
    xpad[(size_t)b * IP2_ + c]       = hi;
    xpad[(size_t)b * IP2_ + IP_ + c] = lo;
}

// decoder inp = concat(prev[:, :67], dec[:, t, 67:82]) -> xpad2 bf16 [B,192] (hi|lo)
__global__ void build_inp_kernel(const float* __restrict__ prev, int pstride,
                                 const float* __restrict__ dec, int t,
                                 u16* __restrict__ xpad) {
    int i = blockIdx.x * 256 + threadIdx.x;
    if (i >= B_ * IP_) return;
    int b = i / IP_, c = i % IP_;
    float v = 0.f;
    if (c < H_)      v = prev[(size_t)b * pstride + c];
    else if (c < I_) v = dec[((size_t)b * TGT_ + t) * I_ + c];
    u16 hi = f2bf(v);
    u16 lo = f2bf(v - bf2f(hi));
    xpad[(size_t)b * IP2_ + c]       = hi;
    xpad[(size_t)b * IP2_ + IP_ + c] = lo;
}

// out[:, t, :] = prev + cfc[:, :67] + bfc    (all fp32)
__global__ void fc_finish_kernel(const float* __restrict__ cfc, const float* __restrict__ prev,
                                 int pstride, const float* __restrict__ bfc,
                                 float* __restrict__ out, int t) {
    int i = blockIdx.x * 256 + threadIdx.x;
    if (i >= B_ * H_) return;
    int b = i / H_, hcol = i % H_;
    out[((size_t)b * TGT_ + t) * H_ + hcol] =
        prev[(size_t)b * pstride + hcol] + cfc[(size_t)b * FCN_ + hcol] + bfc[hcol];
}

// ---------------- GRU gate kernel (fp32 preactivations) ----------------
// gi,gh: f32 [B,3072] (no bias). h: f32 [B,1024] in/out. hbf: bf16 copy, row stride 2048.
__global__ __launch_bounds__(256) void gru_gates_kernel(
    const float* __restrict__ gi, const float* __restrict__ gh,
    const float* __restrict__ bi, const float* __restrict__ bh,
    float* __restrict__ h, u16* __restrict__ hbf) {
    int tid = blockIdx.x * 256 + threadIdx.x;       // B*R/8 threads exactly
    int b  = tid >> 7;
    int j0 = (tid & 127) << 3;
    size_t gbase = (size_t)b * NG_ + j0;

    float gir[8], giz[8], gin[8], ghr[8], ghz[8], ghn[8];
    ldf8(gi + gbase,        gir);
    ldf8(gi + gbase + R_,   giz);
    ldf8(gi + gbase + 2*R_, gin);
    ldf8(gh + gbase,        ghr);
    ldf8(gh + gbase + R_,   ghz);
    ldf8(gh + gbase + 2*R_, ghn);
    float hv[8];
    ldf8(h + (size_t)b * R_ + j0, hv);
    float birv[8], bizv[8], binv[8], bhrv[8], bhzv[8], bhnv[8];
    ldf8(bi + j0,        birv);
    ldf8(bi + R_ + j0,   bizv);
    ldf8(bi + 2*R_ + j0, binv);
    ldf8(bh + j0,        bhrv);
    ldf8(bh + R_ + j0,   bhzv);
    ldf8(bh + 2*R_ + j0, bhnv);

    u16 packed[8];
#pragma unroll
    for (int k = 0; k < 8; k++) {
        float r = sigmf(gir[k] + birv[k] + ghr[k] + bhrv[k]);
        float z = sigmf(giz[k] + bizv[k] + ghz[k] + bhzv[k]);
        float n = tanhfast(gin[k] + binv[k] + r * (ghn[k] + bhnv[k]));
        float nh = (1.f - z) * n + z * hv[k];
        hv[k] = nh;
        packed[k] = f2bf(nh);
    }
    float4 o0 = {hv[0], hv[1], hv[2], hv[3]};
    float4 o1 = {hv[4], hv[5], hv[6], hv[7]};
    *(float4*)(h + (size_t)b * R_ + j0)     = o0;
    *(float4*)(h + (size_t)b * R_ + j0 + 4) = o1;
    *(int4*)(hbf + (size_t)b * K2_ + j0) = *(int4*)packed;
}

// ---------------- GEMM: C[M,N] = A[M,K](lda) @ B[N,K]^T, bf16 in, fp32 acc ----------------
// blockIdx.z selects problem {0,1}; per-z K and lda. CT = float or u16 output.
template<int BM, int BN, int WAVES_M, int WAVES_N, typename CT>
__global__ __launch_bounds__(256) void gemm_bt_kernel(
    const u16* __restrict__ A0, const u16* __restrict__ B0, CT* __restrict__ C0,
    int K0, int lda0,
    const u16* __restrict__ A1, const u16* __restrict__ B1, CT* __restrict__ C1,
    int K1, int lda1,
    int ldc) {
    constexpr int BK = 32;
    constexpr int LDSS = BK + 8;
    constexpr int WM = BM / WAVES_M;
    constexpr int WN = BN / WAVES_N;
    constexpr int TM = WM / 16;
    constexpr int TN = WN / 16;
    constexpr int A_LOADS = BM / 64;
    constexpr int B_LOADS = BN / 64;

    __shared__ __align__(16) u16 As[BM * LDSS];
    __shared__ __align__(16) u16 Bs[BN * LDSS];

    const u16* A  = blockIdx.z ? A1 : A0;
    const u16* Bw = blockIdx.z ? B1 : B0;
    CT*        C  = blockIdx.z ? C1 : C0;
    const int  K   = blockIdx.z ? K1 : K0;
    const int  lda = blockIdx.z ? lda1 : lda0;

    int tid = threadIdx.x;
    int wave = tid >> 6, lane = tid & 63;
    int wm = wave / WAVES_N, wn = wave % WAVES_N;
    int mbase = blockIdx.y * BM;
    int nbase = blockIdx.x * BN;
    int lr = lane & 15;
    int lk = (lane >> 4) * 8;

    f32x4_t acc[TM][TN];
#pragma unroll
    for (int i = 0; i < TM; i++)
#pragma unroll
        for (int j = 0; j < TN; j++) acc[i][j] = (f32x4_t){0.f, 0.f, 0.f, 0.f};

    for (int k0 = 0; k0 < K; k0 += BK) {
        __syncthreads();
#pragma unroll
        for (int i = 0; i < A_LOADS; i++) {
            int g = tid * A_LOADS + i;
            int row = g >> 2, chunk = g & 3;
            int4 v = *(const int4*)(A + (size_t)(mbase + row) * lda + k0 + chunk * 8);
            *(int4*)(As + row * LDSS + chunk * 8) = v;
        }
#pragma unroll
        for (int i = 0; i < B_LOADS; i++) {
            int g = tid * B_LOADS + i;
            int row = g >> 2, chunk = g & 3;
            int4 v = *(const int4*)(Bw + (size_t)(nbase + row) * K + k0 + chunk * 8);
            *(int4*)(Bs + row * LDSS + chunk * 8) = v;
        }
        __syncthreads();
        bf16x8_t af[TM], bfr[TN];
#pragma unroll
        for (int i = 0; i < TM; i++)
            af[i] = *(const bf16x8_t*)(As + (wm * WM + i * 16 + lr) * LDSS + lk);
#pragma unroll
        for (int j = 0; j < TN; j++)
            bfr[j] = *(const bf16x8_t*)(Bs + (wn * WN + j * 16 + lr) * LDSS + lk);
#pragma unroll
        for (int i = 0; i < TM; i++)
#pragma unroll
            for (int j = 0; j < TN; j++)
                acc[i][j] = __builtin_amdgcn_mfma_f32_16x16x32_bf16(af[i], bfr[j], acc[i][j], 0, 0, 0);
    }
    // C/D layout: col = lane&15, row = (lane>>4)*4 + reg  [HW-verified]
    int rr = (lane >> 4) * 4;
#pragma unroll
    for (int i = 0; i < TM; i++) {
#pragma unroll
        for (int r = 0; r < 4; r++) {
            int row = mbase + wm * WM + i * 16 + rr + r;
#pragma unroll
            for (int j = 0; j < TN; j++) {
                int col = nbase + wn * WN + j * 16 + lr;
                float v = acc[i][j][r];
                if constexpr (sizeof(CT) == 2) C[(size_t)row * ldc + col] = f2bf(v);
                else                           C[(size_t)row * ldc + col] = v;
            }
        }
    }
}

// ---------------- host launcher ----------------
extern "C" void kernel_launch(void* const* d_in, const int* in_sizes, int n_in,
                              void* d_out, int out_size, void* d_ws, size_t ws_size,
                              hipStream_t stream) {
    (void)in_sizes; (void)n_in; (void)out_size; (void)ws_size;
    const float* enc = (const float*)d_in[0];
    const float* dec = (const float*)d_in[1];
    const float* Wi1 = (const float*)d_in[2];
    const float* Wh1 = (const float*)d_in[3];
    const float* bi1 = (const float*)d_in[4];
    const float* bh1 = (const float*)d_in[5];
    const float* Wi2 = (const float*)d_in[6];
    const float* Wh2 = (const float*)d_in[7];
    const float* bi2 = (const float*)d_in[8];
    const float* bh2 = (const float*)d_in[9];
    const float* Wfc = (const float*)d_in[10];
    const float* bfc = (const float*)d_in[11];
    float* out = (float*)d_out;

    char* ws = (char*)d_ws;
    size_t off = 0;
    auto alloc = [&](size_t bytes) -> char* {
        char* p = ws + off;
        off += (bytes + 255) & ~(size_t)255;
        return p;
    };
    u16* Wh1b   = (u16*)alloc((size_t)NG_ * R_ * 2);
    u16* Wi2b   = (u16*)alloc((size_t)NG_ * R_ * 2);
    u16* Wh2b   = (u16*)alloc((size_t)NG_ * R_ * 2);
    u16* Wi1pb  = (u16*)alloc((size_t)NG_ * IP2_ * 2);
    u16* Wfcb   = (u16*)alloc((size_t)FCN_ * K2_ * 2);
    u16* s12bf  = (u16*)alloc((size_t)B_ * K2_ * 2);     // [B,2048]: s1bf | s2bf
    float* s1f  = (float*)alloc((size_t)B_ * R_ * 4);
    float* s2f  = (float*)alloc((size_t)B_ * R_ * 4);
    float* g0   = (float*)alloc((size_t)B_ * NG_ * 4);   // gi preact (fp32)
    float* g1   = (float*)alloc((size_t)B_ * NG_ * 4);   // gh preact (fp32)
    u16* xpad2  = (u16*)alloc((size_t)B_ * IP2_ * 2);    // hi|lo split input
    float* cfc  = (float*)alloc((size_t)B_ * FCN_ * 4);

    // zero initial states: s12bf + s1f + s2f are contiguous
    hipMemsetAsync(s12bf, 0,
                   (size_t)B_ * K2_ * 2 + 2 * (size_t)B_ * R_ * 4, stream);

    // weight prep (rerun every call: ws re-poisoned)
    cast_bf16_kernel<<<(NG_ * R_ + 255) / 256, 256, 0, stream>>>(Wh1, Wh1b, NG_ * R_);
    cast_bf16_kernel<<<(NG_ * R_ + 255) / 256, 256, 0, stream>>>(Wi2, Wi2b, NG_ * R_);
    cast_bf16_kernel<<<(NG_ * R_ + 255) / 256, 256, 0, stream>>>(Wh2, Wh2b, NG_ * R_);
    pad_wi1_dup_kernel<<<(NG_ * IP2_ + 255) / 256, 256, 0, stream>>>(Wi1, Wi1pb);
    pad_wfc_kernel<<<(FCN_ * K2_ + 255) / 256, 256, 0, stream>>>(Wfc, Wfcb);

    dim3 gemm_grid2(NG_ / 128, B_ / 128, 2);
    dim3 fc_grid(1, B_ / 64, 1);
    const int padx_blocks  = (B_ * IP_ + 255) / 256;
    const int gates_blocks = B_ * R_ / 8 / 256;
    const int fcf_blocks   = (B_ * H_ + 255) / 256;

    // ---------------- encoder: 49 steps ----------------
    for (int t = 0; t < ENC_STEPS; t++) {
        pad_x_kernel<<<padx_blocks, 256, 0, stream>>>(enc, xpad2, t);
        // z0: gh1 = s1bf @ Wh1^T (K=1024)   z1: gi1 = x(hi|lo) @ Wi1dup^T (K=192)
        gemm_bt_kernel<128, 128, 2, 2, float><<<gemm_grid2, 256, 0, stream>>>(
            s12bf, Wh1b, g1, R_, K2_,
            xpad2, Wi1pb, g0, IP2_, IP2_, NG_);
        gru_gates_kernel<<<gates_blocks, 256, 0, stream>>>(g0, g1, bi1, bh1, s1f, s12bf);
        // z0: gh2 = s2bf_old @ Wh2^T        z1: gi2 = s1bf_new @ Wi2^T
        gemm_bt_kernel<128, 128, 2, 2, float><<<gemm_grid2, 256, 0, stream>>>(
            s12bf + R_, Wh2b, g1, R_, K2_,
            s12bf,      Wi2b, g0, R_, K2_, NG_);
        gru_gates_kernel<<<gates_blocks, 256, 0, stream>>>(g0, g1, bi2, bh2, s2f, s12bf + R_);
    }

    // ---------------- decoder: 25 steps ----------------
    for (int t = 0; t < TGT_; t++) {
        const float* prev;
        int pstride;
        if (t == 0) { prev = dec;                 pstride = TGT_ * I_; }
        else        { prev = out + (t - 1) * H_;  pstride = TGT_ * H_; }
        build_inp_kernel<<<padx_blocks, 256, 0, stream>>>(prev, pstride, dec, t, xpad2);
        gemm_bt_kernel<128, 128, 2, 2, float><<<gemm_grid2, 256, 0, stream>>>(
            s12bf, Wh1b, g1, R_, K2_,
            xpad2, Wi1pb, g0, IP2_, IP2_, NG_);
        gru_gates_kernel<<<gates_blocks, 256, 0, stream>>>(g0, g1, bi1, bh1, s1f, s12bf);
        gemm_bt_kernel<128, 128, 2, 2, float><<<gemm_grid2, 256, 0, stream>>>(
            s12bf + R_, Wh2b, g1, R_, K2_,
            s12bf,      Wi2b, g0, R_, K2_, NG_);
        gru_gates_kernel<<<gates_blocks, 256, 0, stream>>>(g0, g1, bi2, bh2, s2f, s12bf + R_);
        // fc: cfc[B,128] = [s1|s2]bf @ Wfc_pad^T  (K=2048), fp32 out
        gemm_bt_kernel<64, 128, 4, 1, float><<<fc_grid, 256, 0, stream>>>(
            s12bf, Wfcb, cfc, K2_, K2_,
            s12bf, Wfcb, cfc, K2_, K2_, FCN_);
        fc_finish_kernel<<<fcf_blocks, 256, 0, stream>>>(cfc, prev, pstride, bfc, out, t);
    }
}

// Round 3
// 8639.991 us; speedup vs baseline: 1.6492x; 1.6492x over previous
//
#include <hip/hip_runtime.h>
#include <hip/hip_bf16.h>
#include <math.h>

// ---------------- problem constants ----------------
#define B_        4096
#define ENC_STEPS 49     // SRC-1
#define TGT_      25
#define R_        1024
#define H_        67
#define I_        82
#define IP_       96     // input padded to multiple of 32
#define IP2_      192    // split-bf16 (hi|lo) doubled K
#define NG_       3072   // 3*R
#define FCN_      128    // fc output padded 67 -> 128
#define K2_       2048   // 2*R

typedef unsigned short u16;
typedef __attribute__((ext_vector_type(8))) short bf16x8_t;
typedef __attribute__((ext_vector_type(4))) float f32x4_t;

// ---------------- helpers ----------------
__device__ __forceinline__ float bf2f(u16 h) {
    union { unsigned int u; float f; } v; v.u = ((unsigned int)h) << 16; return v.f;
}
__device__ __forceinline__ u16 f2bf(float f) {
    union { unsigned int u; float f; } v; v.f = f;
    unsigned int u = v.u;
    u += 0x7fffu + ((u >> 16) & 1u);   // RNE
    return (u16)(u >> 16);
}
__device__ __forceinline__ float sigmf(float x) { return 1.f / (1.f + __expf(-x)); }
__device__ __forceinline__ float tanhfast(float x) { return 1.f - 2.f / (__expf(2.f * x) + 1.f); }

// async global->LDS, 16B per lane. LDS dest must be wave-uniform base + lane*16,
// which our g = tid + p*256 chunk mapping guarantees (lane-contiguous).
__device__ __forceinline__ void g2l16(const u16* g, u16* l) {
    __builtin_amdgcn_global_load_lds(
        (const __attribute__((address_space(1))) unsigned int*)(const void*)g,
        (__attribute__((address_space(3))) unsigned int*)(void*)l,
        16, 0, 0);
}

// ---------------- weight prep ----------------
__global__ void cast_bf16_kernel(const float* __restrict__ s, u16* __restrict__ d, int n) {
    int i = blockIdx.x * 256 + threadIdx.x;
    if (i < n) d[i] = f2bf(s[i]);
}
// Wi1 [3072,82] -> [3072,192] bf16: cols 0..95 padded Wi1, cols 96..191 duplicate (hi|lo split)
__global__ void pad_wi1_dup_kernel(const float* __restrict__ s, u16* __restrict__ d) {
    int i = blockIdx.x * 256 + threadIdx.x;
    if (i >= NG_ * IP2_) return;
    int r = i / IP2_, c = i % IP2_;
    int cc = (c < IP_) ? c : c - IP_;
    d[i] = (cc < I_) ? f2bf(s[r * I_ + cc]) : (u16)0;
}
// Wfc [67,2048] -> [128,2048] bf16, zero-padded N rows
__global__ void pad_wfc_kernel(const float* __restrict__ s, u16* __restrict__ d) {
    int i = blockIdx.x * 256 + threadIdx.x;
    if (i >= FCN_ * K2_) return;
    int r = i / K2_, c = i % K2_;
    d[i] = (r < H_) ? f2bf(s[r * K2_ + c]) : (u16)0;
}

// all encoder inputs -> xall bf16 [ENC][B][192] (hi|lo split), one launch
__global__ void pad_all_x_kernel(const float* __restrict__ enc, u16* __restrict__ xall) {
    int i = blockIdx.x * 256 + threadIdx.x;
    if (i >= B_ * ENC_STEPS * IP_) return;
    int c = i % IP_;
    int t = (i / IP_) % ENC_STEPS;
    int b = i / (IP_ * ENC_STEPS);
    float v = (c < I_) ? enc[((size_t)b * ENC_STEPS + t) * I_ + c] : 0.f;
    u16 hi = f2bf(v);
    u16 lo = f2bf(v - bf2f(hi));
    size_t base = ((size_t)t * B_ + b) * IP2_;
    xall[base + c]       = hi;
    xall[base + IP_ + c] = lo;
}

// decoder inp = concat(prev[:, :67], dec[:, t, 67:82]) -> xpad2 bf16 [B,192] (hi|lo)
__global__ void build_inp_kernel(const float* __restrict__ prev, int pstride,
                                 const float* __restrict__ dec, int t,
                                 u16* __restrict__ xpad) {
    int i = blockIdx.x * 256 + threadIdx.x;
    if (i >= B_ * IP_) return;
    int b = i / IP_, c = i % IP_;
    float v = 0.f;
    if (c < H_)      v = prev[(size_t)b * pstride + c];
    else if (c < I_) v = dec[((size_t)b * TGT_ + t) * I_ + c];
    u16 hi = f2bf(v);
    u16 lo = f2bf(v - bf2f(hi));
    xpad[(size_t)b * IP2_ + c]       = hi;
    xpad[(size_t)b * IP2_ + IP_ + c] = lo;
}

// ---------------- fused GRU step (one layer) ----------------
// Tile: 128 batch rows x 64 R-cols x 3 gates. Two K passes (x then h) into the
// same accumulators for r/z; separate x/h accumulators for n (r multiplies only gh_n).
// Epilogue: gates + state update; writes fp32 state in-place and bf16 state to the
// ping-pong NEXT buffer (other blocks still read the CUR buffer during their K-loop).
template<int KX>
__global__ __launch_bounds__(256, 2) void gru_step_kernel(
    const u16* __restrict__ Ax, int ldax,       // [B, ldax] bf16 input
    const u16* __restrict__ Wx,                 // [3R, KX] bf16
    const u16* __restrict__ Ah, int ldah,       // [B, ldah] bf16 state (cur)
    const u16* __restrict__ Wh,                 // [3R, 1024] bf16
    const float* __restrict__ bi, const float* __restrict__ bh,
    float* __restrict__ hf,                     // [B, R] fp32 state, in/out (in-place per-tile)
    u16* __restrict__ hout)                     // bf16 state out (nxt buffer), row stride K2_
{
    __shared__ __align__(16) u16 As[128 * 32];       // 8 KB
    __shared__ __align__(16) u16 Ws[3 * 64 * 32];    // 12 KB

    const int tid  = threadIdx.x;
    const int lane = tid & 63, wave = tid >> 6;
    const int wm = wave >> 1, wn = wave & 1;          // 2x2 waves: WM=64, WN=32
    const int mbase = blockIdx.y * 128;
    const int nbase = blockIdx.x * 64;
    const int lr = lane & 15, lk = (lane >> 4) * 8;

    f32x4_t acc_r[4][2], acc_z[4][2], acc_xn[4][2], acc_hn[4][2];
#pragma unroll
    for (int i = 0; i < 4; i++)
#pragma unroll
        for (int j = 0; j < 2; j++) {
            acc_r[i][j]  = (f32x4_t){0,0,0,0};
            acc_z[i][j]  = (f32x4_t){0,0,0,0};
            acc_xn[i][j] = (f32x4_t){0,0,0,0};
            acc_hn[i][j] = (f32x4_t){0,0,0,0};
        }

    // ---- pass 1: x @ Wx^T ----
    for (int k0 = 0; k0 < KX; k0 += 32) {
        __syncthreads();
#pragma unroll
        for (int p = 0; p < 2; p++) {
            int g = tid + p * 256;                   // 512 chunks = 128 rows * 4
            g2l16(Ax + (size_t)(mbase + (g >> 2)) * ldax + k0 + (g & 3) * 8, As + g * 8);
        }
#pragma unroll
        for (int p = 0; p < 3; p++) {
            int q = tid + p * 256;                   // 768 chunks = 3 gates * 64 rows * 4
            int gate = q >> 8, rg = (q >> 2) & 63, cw = q & 3;
            g2l16(Wx + ((size_t)gate * R_ + nbase + rg) * KX + k0 + cw * 8, Ws + q * 8);
        }
        __syncthreads();
        bf16x8_t a_f[4], w_r[2], w_z[2], w_n[2];
#pragma unroll
        for (int i = 0; i < 4; i++)
            a_f[i] = *(const bf16x8_t*)(As + (wm * 64 + i * 16 + lr) * 32 + lk);
#pragma unroll
        for (int j = 0; j < 2; j++) {
            int c = wn * 32 + j * 16 + lr;
            w_r[j] = *(const bf16x8_t*)(Ws + c * 32 + lk);
            w_z[j] = *(const bf16x8_t*)(Ws + (64 + c) * 32 + lk);
            w_n[j] = *(const bf16x8_t*)(Ws + (128 + c) * 32 + lk);
        }
#pragma unroll
        for (int i = 0; i < 4; i++)
#pragma unroll
            for (int j = 0; j < 2; j++) {
                acc_r[i][j]  = __builtin_amdgcn_mfma_f32_16x16x32_bf16(a_f[i], w_r[j], acc_r[i][j], 0, 0, 0);
                acc_z[i][j]  = __builtin_amdgcn_mfma_f32_16x16x32_bf16(a_f[i], w_z[j], acc_z[i][j], 0, 0, 0);
                acc_xn[i][j] = __builtin_amdgcn_mfma_f32_16x16x32_bf16(a_f[i], w_n[j], acc_xn[i][j], 0, 0, 0);
            }
    }

    // ---- pass 2: h_old @ Wh^T ----
    for (int k0 = 0; k0 < R_; k0 += 32) {
        __syncthreads();
#pragma unroll
        for (int p = 0; p < 2; p++) {
            int g = tid + p * 256;
            g2l16(Ah + (size_t)(mbase + (g >> 2)) * ldah + k0 + (g & 3) * 8, As + g * 8);
        }
#pragma unroll
        for (int p = 0; p < 3; p++) {
            int q = tid + p * 256;
            int gate = q >> 8, rg = (q >> 2) & 63, cw = q & 3;
            g2l16(Wh + ((size_t)gate * R_ + nbase + rg) * R_ + k0 + cw * 8, Ws + q * 8);
        }
        __syncthreads();
        bf16x8_t a_f[4], w_r[2], w_z[2], w_n[2];
#pragma unroll
        for (int i = 0; i < 4; i++)
            a_f[i] = *(const bf16x8_t*)(As + (wm * 64 + i * 16 + lr) * 32 + lk);
#pragma unroll
        for (int j = 0; j < 2; j++) {
            int c = wn * 32 + j * 16 + lr;
            w_r[j] = *(const bf16x8_t*)(Ws + c * 32 + lk);
            w_z[j] = *(const bf16x8_t*)(Ws + (64 + c) * 32 + lk);
            w_n[j] = *(const bf16x8_t*)(Ws + (128 + c) * 32 + lk);
        }
#pragma unroll
        for (int i = 0; i < 4; i++)
#pragma unroll
            for (int j = 0; j < 2; j++) {
                acc_r[i][j]  = __builtin_amdgcn_mfma_f32_16x16x32_bf16(a_f[i], w_r[j], acc_r[i][j], 0, 0, 0);
                acc_z[i][j]  = __builtin_amdgcn_mfma_f32_16x16x32_bf16(a_f[i], w_z[j], acc_z[i][j], 0, 0, 0);
                acc_hn[i][j] = __builtin_amdgcn_mfma_f32_16x16x32_bf16(a_f[i], w_n[j], acc_hn[i][j], 0, 0, 0);
            }
    }

    // ---- epilogue: gates + state update ----
    // C/D layout: col = lane&15, row = (lane>>4)*4 + reg   [HW-verified]
    const int rr2 = (lane >> 4) * 4;
#pragma unroll
    for (int j = 0; j < 2; j++) {
        const int col = nbase + wn * 32 + j * 16 + lr;
        const float b_ir = bi[col],          b_hr = bh[col];
        const float b_iz = bi[R_ + col],     b_hz = bh[R_ + col];
        const float b_in = bi[2 * R_ + col], b_hn = bh[2 * R_ + col];
#pragma unroll
        for (int i = 0; i < 4; i++) {
#pragma unroll
            for (int r = 0; r < 4; r++) {
                const int row = mbase + wm * 64 + i * 16 + rr2 + r;
                const float hold = hf[(size_t)row * R_ + col];
                const float rv = sigmf(acc_r[i][j][r] + b_ir + b_hr);
                const float zv = sigmf(acc_z[i][j][r] + b_iz + b_hz);
                const float nv = tanhfast(acc_xn[i][j][r] + b_in + rv * (acc_hn[i][j][r] + b_hn));
                const float hn = (1.f - zv) * nv + zv * hold;
                hf[(size_t)row * R_ + col] = hn;
                hout[(size_t)row * K2_ + col] = f2bf(hn);
            }
        }
    }
}

// ---------------- FC: 4-way K-split partial GEMM ----------------
// part[kc][B][128] = s12[:, kc*512:(kc+1)*512] @ Wfc[:, same]^T
__global__ __launch_bounds__(256) void fc_part_kernel(
    const u16* __restrict__ A, const u16* __restrict__ W, float* __restrict__ part) {
    __shared__ __align__(16) u16 As[64 * 32];     // 4 KB
    __shared__ __align__(16) u16 Bs[128 * 32];    // 8 KB
    const int tid  = threadIdx.x;
    const int lane = tid & 63, wave = tid >> 6;
    const int wm = wave >> 1, wn = wave & 1;      // WM=32, WN=64
    const int mbase = blockIdx.y * 64;
    const int kbase = blockIdx.x * 512;
    const int lr = lane & 15, lk = (lane >> 4) * 8;

    f32x4_t acc[2][4];
#pragma unroll
    for (int i = 0; i < 2; i++)
#pragma unroll
        for (int j = 0; j < 4; j++) acc[i][j] = (f32x4_t){0, 0, 0, 0};

    for (int k0 = 0; k0 < 512; k0 += 32) {
        __syncthreads();
        {
            int g = tid;                           // 256 chunks = 64 rows * 4
            g2l16(A + (size_t)(mbase + (g >> 2)) * K2_ + kbase + k0 + (g & 3) * 8, As + g * 8);
        }
#pragma unroll
        for (int p = 0; p < 2; p++) {
            int q = tid + p * 256;                 // 512 chunks = 128 rows * 4
            g2l16(W + (size_t)(q >> 2) * K2_ + kbase + k0 + (q & 3) * 8, Bs + q * 8);
        }
        __syncthreads();
        bf16x8_t a_f[2], b_f[4];
#pragma unroll
        for (int i = 0; i < 2; i++)
            a_f[i] = *(const bf16x8_t*)(As + (wm * 32 + i * 16 + lr) * 32 + lk);
#pragma unroll
        for (int j = 0; j < 4; j++)
            b_f[j] = *(const bf16x8_t*)(Bs + (wn * 64 + j * 16 + lr) * 32 + lk);
#pragma unroll
        for (int i = 0; i < 2; i++)
#pragma unroll
            for (int j = 0; j < 4; j++)
                acc[i][j] = __builtin_amdgcn_mfma_f32_16x16x32_bf16(a_f[i], b_f[j], acc[i][j], 0, 0, 0);
    }
    const int rr2 = (lane >> 4) * 4;
#pragma unroll
    for (int i = 0; i < 2; i++)
#pragma unroll
        for (int r = 0; r < 4; r++) {
            int row = mbase + wm * 32 + i * 16 + rr2 + r;
#pragma unroll
            for (int j = 0; j < 4; j++) {
                int col = wn * 64 + j * 16 + lr;
                part[((size_t)blockIdx.x * B_ + row) * FCN_ + col] = acc[i][j][r];
            }
        }
}

// out[:, t, :] = prev + sum(4 partials)[:, :67] + bfc  (deterministic reduce)
__global__ void fc_finish_kernel(const float* __restrict__ part, const float* __restrict__ prev,
                                 int pstride, const float* __restrict__ bfc,
                                 float* __restrict__ out, int t) {
    int i = blockIdx.x * 256 + threadIdx.x;
    if (i >= B_ * H_) return;
    int b = i / H_, c = i % H_;
    size_t idx = (size_t)b * FCN_ + c;
    const size_t S = (size_t)B_ * FCN_;
    float s = (part[idx] + part[S + idx]) + (part[2 * S + idx] + part[3 * S + idx]);
    out[((size_t)b * TGT_ + t) * H_ + c] = prev[(size_t)b * pstride + c] + s + bfc[c];
}

// ---------------- host launcher ----------------
extern "C" void kernel_launch(void* const* d_in, const int* in_sizes, int n_in,
                              void* d_out, int out_size, void* d_ws, size_t ws_size,
                              hipStream_t stream) {
    (void)in_sizes; (void)n_in; (void)out_size; (void)ws_size;
    const float* enc = (const float*)d_in[0];
    const float* dec = (const float*)d_in[1];
    const float* Wi1 = (const float*)d_in[2];
    const float* Wh1 = (const float*)d_in[3];
    const float* bi1 = (const float*)d_in[4];
    const float* bh1 = (const float*)d_in[5];
    const float* Wi2 = (const float*)d_in[6];
    const float* Wh2 = (const float*)d_in[7];
    const float* bi2 = (const float*)d_in[8];
    const float* bh2 = (const float*)d_in[9];
    const float* Wfc = (const float*)d_in[10];
    const float* bfc = (const float*)d_in[11];
    float* out = (float*)d_out;

    char* ws = (char*)d_ws;
    size_t off = 0;
    auto alloc = [&](size_t bytes) -> char* {
        char* p = ws + off;
        off += (bytes + 255) & ~(size_t)255;
        return p;
    };
    u16* Wh1b  = (u16*)alloc((size_t)NG_ * R_ * 2);
    u16* Wi2b  = (u16*)alloc((size_t)NG_ * R_ * 2);
    u16* Wh2b  = (u16*)alloc((size_t)NG_ * R_ * 2);
    u16* Wi1pb = (u16*)alloc((size_t)NG_ * IP2_ * 2);
    u16* Wfcb  = (u16*)alloc((size_t)FCN_ * K2_ * 2);
    // contiguous zero-init group: sbuf0, s1f, s2f
    u16* sbuf0 = (u16*)alloc((size_t)B_ * K2_ * 2);
    float* s1f = (float*)alloc((size_t)B_ * R_ * 4);
    float* s2f = (float*)alloc((size_t)B_ * R_ * 4);
    u16* sbuf1 = (u16*)alloc((size_t)B_ * K2_ * 2);
    u16* xall  = (u16*)alloc((size_t)ENC_STEPS * B_ * IP2_ * 2);
    u16* xpad2 = (u16*)alloc((size_t)B_ * IP2_ * 2);
    float* cfcp = (float*)alloc((size_t)4 * B_ * FCN_ * 4);
    u16* sbuf[2] = { sbuf0, sbuf1 };

    hipMemsetAsync(sbuf0, 0,
                   (size_t)B_ * K2_ * 2 + 2 * (size_t)B_ * R_ * 4, stream);

    // weight prep (rerun every call: ws re-poisoned)
    cast_bf16_kernel<<<(NG_ * R_ + 255) / 256, 256, 0, stream>>>(Wh1, Wh1b, NG_ * R_);
    cast_bf16_kernel<<<(NG_ * R_ + 255) / 256, 256, 0, stream>>>(Wi2, Wi2b, NG_ * R_);
    cast_bf16_kernel<<<(NG_ * R_ + 255) / 256, 256, 0, stream>>>(Wh2, Wh2b, NG_ * R_);
    pad_wi1_dup_kernel<<<(NG_ * IP2_ + 255) / 256, 256, 0, stream>>>(Wi1, Wi1pb);
    pad_wfc_kernel<<<(FCN_ * K2_ + 255) / 256, 256, 0, stream>>>(Wfc, Wfcb);
    pad_all_x_kernel<<<(B_ * ENC_STEPS * IP_ + 255) / 256, 256, 0, stream>>>(enc, xall);

    dim3 gru_grid(R_ / 64, B_ / 128, 1);       // 16 x 32 = 512 blocks
    dim3 fc_grid(4, B_ / 64, 1);               // 256 blocks
    const int binp_blocks = (B_ * IP_ + 255) / 256;
    const int fcf_blocks  = (B_ * H_ + 255) / 256;

    int phase = 0;

    // ---------------- encoder: 49 steps ----------------
    for (int t = 0; t < ENC_STEPS; t++) {
        u16* cur = sbuf[phase];
        u16* nxt = sbuf[phase ^ 1];
        gru_step_kernel<IP2_><<<gru_grid, 256, 0, stream>>>(
            xall + (size_t)t * B_ * IP2_, IP2_, Wi1pb,
            cur, K2_, Wh1b, bi1, bh1, s1f, nxt);
        gru_step_kernel<R_><<<gru_grid, 256, 0, stream>>>(
            nxt, K2_, Wi2b,
            cur + R_, K2_, Wh2b, bi2, bh2, s2f, nxt + R_);
        phase ^= 1;
    }

    // ---------------- decoder: 25 steps ----------------
    for (int t = 0; t < TGT_; t++) {
        const float* prev;
        int pstride;
        if (t == 0) { prev = dec;                 pstride = TGT_ * I_; }
        else        { prev = out + (t - 1) * H_;  pstride = TGT_ * H_; }
        u16* cur = sbuf[phase];
        u16* nxt = sbuf[phase ^ 1];
        build_inp_kernel<<<binp_blocks, 256, 0, stream>>>(prev, pstride, dec, t, xpad2);
        gru_step_kernel<IP2_><<<gru_grid, 256, 0, stream>>>(
            xpad2, IP2_, Wi1pb,
            cur, K2_, Wh1b, bi1, bh1, s1f, nxt);
        gru_step_kernel<R_><<<gru_grid, 256, 0, stream>>>(
            nxt, K2_, Wi2b,
            cur + R_, K2_, Wh2b, bi2, bh2, s2f, nxt + R_);
        fc_part_kernel<<<fc_grid, 256, 0, stream>>>(nxt, Wfcb, cfcp);
        fc_finish_kernel<<<fcf_blocks, 256, 0, stream>>>(cfcp, prev, pstride, bfc, out, t);
        phase ^= 1;
    }
}